// Round 1
// baseline (104.104 us; speedup 1.0000x reference)
//
#include <hip/hip_runtime.h>
#include <math.h>

#define T_TOK 4096
#define DD 64
#define NLAND 8
#define NHEADS 64          // B*H = 4*16
#define SEG 512            // T_TOK / NLAND
#define NCHUNK 8
#define CHUNK 512          // T_TOK / NCHUNK
#define SCALE 0.125f

// workspace layout (in floats)
#define QL_OFF   0                      // [64][8][64]   = 32768
#define KL_OFF   32768                  // [64][8][64]   = 32768
#define K2_OFF   65536                  // [64][8][8]    = 4096
#define CS_OFF   69632                  // [64][8]       = 512
#define PINV_OFF 70144                  // [64][8][8]    = 4096
#define PD_OFF   74240                  // [64][8][8]    = 4096  (head, chunk, m)
#define PA_OFF   78336                  // [64][8][8][64]= 262144
#define K3V_OFF  340480                 // [64][8][64]   = 32768
// total = 373248 floats = ~1.43 MB

// ---------------------------------------------------------------------------
// 1. Landmarks: segment means of 512 consecutive head-tokens (contiguous 32768
//    floats per (head, landmark)).  One block per (head, landmark).
// ---------------------------------------------------------------------------
__global__ __launch_bounds__(256) void landmark_kernel(
    const float* __restrict__ q, const float* __restrict__ k,
    float* __restrict__ ws) {
  int hb = blockIdx.x >> 3;            // 0..63
  int m  = blockIdx.x & 7;             // 0..7
  size_t base = (size_t)hb * (T_TOK * DD) + (size_t)m * (SEG * DD);
  const float4* q4 = (const float4*)(q + base);
  const float4* k4 = (const float4*)(k + base);
  int tid = threadIdx.x;

  float4 aq = make_float4(0.f, 0.f, 0.f, 0.f);
  float4 ak = make_float4(0.f, 0.f, 0.f, 0.f);
  // 32768 floats = 8192 float4; dims covered by a thread are fixed: (tid&15)*4..+3
#pragma unroll 4
  for (int it = 0; it < 32; ++it) {
    float4 x = q4[it * 256 + tid];
    aq.x += x.x; aq.y += x.y; aq.z += x.z; aq.w += x.w;
    float4 y = k4[it * 256 + tid];
    ak.x += y.x; ak.y += y.y; ak.z += y.z; ak.w += y.w;
  }
  __shared__ float4 redq[16][16];
  __shared__ float4 redk[16][16];
  int g = tid >> 4, d4 = tid & 15;
  redq[g][d4] = aq;
  redk[g][d4] = ak;
  __syncthreads();
  if (tid < 16) {
    float4 sq = make_float4(0.f, 0.f, 0.f, 0.f);
    float4 sk = make_float4(0.f, 0.f, 0.f, 0.f);
    for (int gg = 0; gg < 16; ++gg) {
      float4 a = redq[gg][tid];
      sq.x += a.x; sq.y += a.y; sq.z += a.z; sq.w += a.w;
      float4 b = redk[gg][tid];
      sk.x += b.x; sk.y += b.y; sk.z += b.z; sk.w += b.w;
    }
    const float inv = 1.f / (float)SEG;
    sq.x *= inv; sq.y *= inv; sq.z *= inv; sq.w *= inv;
    sk.x *= inv; sk.y *= inv; sk.z *= inv; sk.w *= inv;
    ((float4*)(ws + QL_OFF + hb * 512 + m * 64))[tid] = sq;
    ((float4*)(ws + KL_OFF + hb * 512 + m * 64))[tid] = sk;
  }
}

// ---------------------------------------------------------------------------
// 2. kernel_2 = softmax(q_l k_l^T * scale) rows, plus column sums.
// ---------------------------------------------------------------------------
__global__ __launch_bounds__(64) void k2_kernel(float* __restrict__ ws) {
  int hb = blockIdx.x;
  int tid = threadIdx.x;
  int i = tid >> 3, j = tid & 7;
  const float* ql = ws + QL_OFF + hb * 512;
  const float* kl = ws + KL_OFF + hb * 512;
  float dot = 0.f;
#pragma unroll
  for (int d = 0; d < 64; ++d) dot += ql[i * 64 + d] * kl[j * 64 + d];
  float l = dot * SCALE;
  __shared__ float lds[8][9];
  lds[i][j] = l;
  __syncthreads();
  float mx = -1e30f;
  for (int jj = 0; jj < 8; ++jj) mx = fmaxf(mx, lds[i][jj]);
  float s = 0.f;
  for (int jj = 0; jj < 8; ++jj) s += __expf(lds[i][jj] - mx);
  float val = __expf(l - mx) / s;
  __syncthreads();
  lds[i][j] = val;
  ws[K2_OFF + hb * 64 + tid] = val;
  __syncthreads();
  if (tid < 8) {
    float cs = 0.f;
    for (int ii = 0; ii < 8; ++ii) cs += lds[ii][tid];
    ws[CS_OFF + hb * 8 + tid] = cs;
  }
}

// ---------------------------------------------------------------------------
// 3. Newton-Schulz pseudo-inverse.  Global max over all 512 column sums,
//    then 6 iterations of 8x8 matmuls in LDS.  One block (64 thr) per head.
// ---------------------------------------------------------------------------
__global__ __launch_bounds__(64) void pinv_kernel(float* __restrict__ ws) {
  int hb = blockIdx.x;
  int tid = threadIdx.x;
  // global max (column sums are positive)
  float mx = 0.f;
  for (int t = 0; t < 8; ++t) mx = fmaxf(mx, ws[CS_OFF + t * 64 + tid]);
  for (int off = 32; off; off >>= 1) mx = fmaxf(mx, __shfl_xor(mx, off));
  float inv = 1.f / mx;

  int i = tid >> 3, j = tid & 7;
  __shared__ float K[8][9], V[8][9], X[8][9], Y[8][9];
  K[i][j] = ws[K2_OFF + hb * 64 + tid];
  V[i][j] = ws[K2_OFF + hb * 64 + j * 8 + i] * inv;  // (1/max) * K^T
  __syncthreads();
  for (int it = 0; it < 6; ++it) {
    float x = 0.f;
    for (int kk = 0; kk < 8; ++kk) x += K[i][kk] * V[kk][j];
    X[i][j] = x;
    __syncthreads();
    // Bm = X @ (7I - X) = 7X - X@X
    float bm = 0.f;
    for (int kk = 0; kk < 8; ++kk) bm += X[i][kk] * X[kk][j];
    bm = 7.f * x - bm;
    Y[i][j] = bm;
    __syncthreads();
    // Dm = X @ (15I - Bm) = 15X - X@Bm
    float dm = 0.f;
    for (int kk = 0; kk < 8; ++kk) dm += X[i][kk] * Y[kk][j];
    dm = 15.f * x - dm;
    __syncthreads();
    Y[i][j] = dm;
    __syncthreads();
    // Vn = 0.25 * V @ (13I - Dm) = 0.25*(13V - V@Dm)
    float vd = 0.f;
    for (int kk = 0; kk < 8; ++kk) vd += V[i][kk] * Y[kk][j];
    float vn = 0.25f * (13.f * V[i][j] - vd);
    __syncthreads();
    V[i][j] = vn;
    __syncthreads();
  }
  ws[PINV_OFF + hb * 64 + tid] = V[i][j];
}

// ---------------------------------------------------------------------------
// 4. kernel_3 @ v partials: per (head, 512-token chunk) accumulate
//    sum_t exp(q_l . k_t * scale) * v_t  and the denominators.
//    Logits are tiny (|l| << 1) so no max subtraction is needed.
// ---------------------------------------------------------------------------
#define PADT 68
__global__ __launch_bounds__(256) void k3v_partial_kernel(
    const float* __restrict__ k, const float* __restrict__ v,
    float* __restrict__ ws) {
  int hb = blockIdx.x >> 3;
  int c  = blockIdx.x & 7;
  int tid = threadIdx.x;
  __shared__ float ql[8][65];
  __shared__ float kt[64][PADT];
  __shared__ float vt[64][PADT];
  __shared__ float pl[64][8];

  if (tid < 128) {
    float4 x = ((const float4*)(ws + QL_OFF + hb * 512))[tid];
    int m = tid >> 4, d4 = (tid & 15) * 4;
    ql[m][d4] = x.x; ql[m][d4 + 1] = x.y; ql[m][d4 + 2] = x.z; ql[m][d4 + 3] = x.w;
  }

  size_t base = (size_t)hb * (T_TOK * DD) + (size_t)c * (CHUNK * DD);
  float a0 = 0.f, a1 = 0.f;   // two (m,d) accumulators: m0=tid>>6, m1=m0+4, d=tid&63
  float dden = 0.f;           // threads 0..7: denominator for m=tid

  for (int tile = 0; tile < 8; ++tile) {
    __syncthreads();  // protects ql on tile 0 and pl/kt/vt reuse afterwards
    const float4* k4 = (const float4*)(k + base + (size_t)tile * 64 * DD);
    const float4* v4 = (const float4*)(v + base + (size_t)tile * 64 * DD);
#pragma unroll
    for (int it = 0; it < 4; ++it) {
      int f4 = it * 256 + tid;
      int t = f4 >> 4, d4 = (f4 & 15) << 2;
      float4 x = k4[f4];
      kt[t][d4] = x.x; kt[t][d4 + 1] = x.y; kt[t][d4 + 2] = x.z; kt[t][d4 + 3] = x.w;
      float4 y = v4[f4];
      vt[t][d4] = y.x; vt[t][d4 + 1] = y.y; vt[t][d4 + 2] = y.z; vt[t][d4 + 3] = y.w;
    }
    __syncthreads();
#pragma unroll
    for (int p = 0; p < 2; ++p) {
      int idx = p * 256 + tid;
      int t = idx >> 3, m = idx & 7;
      float dot = 0.f;
#pragma unroll
      for (int d = 0; d < 64; ++d) dot += kt[t][d] * ql[m][d];
      pl[t][m] = __expf(dot * SCALE);
    }
    __syncthreads();
    {
      int m0 = tid >> 6;
      int d0 = tid & 63;
      float s0 = 0.f, s1 = 0.f;
#pragma unroll
      for (int t = 0; t < 64; ++t) {
        float vv = vt[t][d0];
        s0 += pl[t][m0] * vv;
        s1 += pl[t][m0 + 4] * vv;
      }
      a0 += s0;
      a1 += s1;
    }
    if (tid < 8) {
      float s = 0.f;
      for (int t = 0; t < 64; ++t) s += pl[t][tid];
      dden += s;
    }
  }
  int m0 = tid >> 6, d0 = tid & 63;
  ws[PA_OFF + (((size_t)hb * 8 + c) * 8 + m0) * 64 + d0] = a0;
  ws[PA_OFF + (((size_t)hb * 8 + c) * 8 + m0 + 4) * 64 + d0] = a1;
  if (tid < 8) ws[PD_OFF + (hb * 8 + c) * 8 + tid] = dden;
}

// ---------------------------------------------------------------------------
// 5. Reduce chunk partials -> k3v[head][8][64], normalized.
// ---------------------------------------------------------------------------
__global__ __launch_bounds__(256) void k3v_reduce_kernel(float* __restrict__ ws) {
  int hb = blockIdx.x;
  int tid = threadIdx.x;
#pragma unroll
  for (int p = 0; p < 2; ++p) {
    int idx = p * 256 + tid;
    int m = idx >> 6, d = idx & 63;
    float s = 0.f, den = 0.f;
    for (int c = 0; c < 8; ++c) {
      s += ws[PA_OFF + (((size_t)hb * 8 + c) * 8 + m) * 64 + d];
      den += ws[PD_OFF + (hb * 8 + c) * 8 + m];
    }
    ws[K3V_OFF + hb * 512 + idx] = s / den;
  }
}

// ---------------------------------------------------------------------------
// 6. Output: per 64-token tile of one head:
//    w = softmax(q_t . k_l * scale)  (8-wide);  u = w @ pinv;  out = u @ k3v.
// ---------------------------------------------------------------------------
__global__ __launch_bounds__(256) void out_kernel(
    const float* __restrict__ q, float* __restrict__ out,
    const float* __restrict__ ws) {
  int hb = blockIdx.x >> 6;
  int tt = blockIdx.x & 63;
  int tid = threadIdx.x;
  __shared__ float qt[64][PADT];
  __shared__ float klh[8][65];
  __shared__ float k3v[8][65];
  __shared__ float pv[8][9];
  __shared__ float lsm[64][9];
  __shared__ float uu[64][9];

  if (tid < 128) {
    int m = tid >> 4, d4 = (tid & 15) * 4;
    float4 x = ((const float4*)(ws + KL_OFF + hb * 512))[tid];
    klh[m][d4] = x.x; klh[m][d4 + 1] = x.y; klh[m][d4 + 2] = x.z; klh[m][d4 + 3] = x.w;
    float4 y = ((const float4*)(ws + K3V_OFF + hb * 512))[tid];
    k3v[m][d4] = y.x; k3v[m][d4 + 1] = y.y; k3v[m][d4 + 2] = y.z; k3v[m][d4 + 3] = y.w;
  }
  if (tid < 64) pv[tid >> 3][tid & 7] = ws[PINV_OFF + hb * 64 + tid];

  size_t base = (size_t)hb * (T_TOK * DD) + (size_t)tt * (64 * DD);
  const float4* q4 = (const float4*)(q + base);
#pragma unroll
  for (int it = 0; it < 4; ++it) {
    int f4 = it * 256 + tid;
    int t = f4 >> 4, d4 = (f4 & 15) << 2;
    float4 x = q4[f4];
    qt[t][d4] = x.x; qt[t][d4 + 1] = x.y; qt[t][d4 + 2] = x.z; qt[t][d4 + 3] = x.w;
  }
  __syncthreads();
#pragma unroll
  for (int p = 0; p < 2; ++p) {
    int idx = p * 256 + tid;
    int t = idx >> 3, m = idx & 7;
    float dot = 0.f;
#pragma unroll
    for (int d = 0; d < 64; ++d) dot += qt[t][d] * klh[m][d];
    lsm[t][m] = dot * SCALE;
  }
  __syncthreads();
  if (tid < 64) {
    int t = tid;
    float l[8];
    float mx = -1e30f;
#pragma unroll
    for (int m = 0; m < 8; ++m) { l[m] = lsm[t][m]; mx = fmaxf(mx, l[m]); }
    float s = 0.f;
#pragma unroll
    for (int m = 0; m < 8; ++m) { l[m] = __expf(l[m] - mx); s += l[m]; }
    float is = 1.f / s;
#pragma unroll
    for (int m = 0; m < 8; ++m) l[m] *= is;
#pragma unroll
    for (int j = 0; j < 8; ++j) {
      float u = 0.f;
#pragma unroll
      for (int m = 0; m < 8; ++m) u += l[m] * pv[m][j];
      uu[t][j] = u;
    }
  }
  __syncthreads();
  float4* o4 = (float4*)(out + base);
#pragma unroll
  for (int it = 0; it < 4; ++it) {
    int f4 = it * 256 + tid;
    int t = f4 >> 4, d4 = (f4 & 15) << 2;
    float r0 = 0.f, r1 = 0.f, r2 = 0.f, r3 = 0.f;
#pragma unroll
    for (int m = 0; m < 8; ++m) {
      float u = uu[t][m];
      r0 += u * k3v[m][d4];
      r1 += u * k3v[m][d4 + 1];
      r2 += u * k3v[m][d4 + 2];
      r3 += u * k3v[m][d4 + 3];
    }
    o4[f4] = make_float4(r0, r1, r2, r3);
  }
}

// ---------------------------------------------------------------------------
extern "C" void kernel_launch(void* const* d_in, const int* in_sizes, int n_in,
                              void* d_out, int out_size, void* d_ws, size_t ws_size,
                              hipStream_t stream) {
  const float* q = (const float*)d_in[0];
  const float* k = (const float*)d_in[1];
  const float* v = (const float*)d_in[2];
  float* out = (float*)d_out;
  float* ws = (float*)d_ws;

  landmark_kernel<<<NHEADS * NLAND, 256, 0, stream>>>(q, k, ws);
  k3v_partial_kernel<<<NHEADS * NCHUNK, 256, 0, stream>>>(k, v, ws);
  k2_kernel<<<NHEADS, 64, 0, stream>>>(ws);
  pinv_kernel<<<NHEADS, 64, 0, stream>>>(ws);
  k3v_reduce_kernel<<<NHEADS, 256, 0, stream>>>(ws);
  out_kernel<<<NHEADS * 64, 256, 0, stream>>>(q, out, ws);
}